// Round 16
// baseline (138.650 us; speedup 1.0000x reference)
//
#include <hip/hip_runtime.h>

#define NTRAIN 32768
#define NBDY   4096
#define PHYS_BLOCKS (NTRAIN / 16)   // 2048 blocks, 16 pts each
#define BDY_BLOCKS  256             // 64 pts/block, 64 blocks per batch
// r16: boundary blocks FIRST ([0,256)), physics [256,2304). With LDS=20480B
// exactly 8 blocks/CU are resident (2048); boundary-last left a 1-block/CU
// tail pass. Boundary-first overlaps it with physics.

typedef _Float16 f16x8 __attribute__((ext_vector_type(8)));
typedef __fp16   fp16x2 __attribute__((ext_vector_type(2)));
typedef float    f32x4 __attribute__((ext_vector_type(4)));

union FragU { uint4 q; f16x8 b; _Float16 e[8]; };
union F4  { float4 v; float f[4]; };
union U2h { _Float16 e[4]; uint2 d; };
union H2  { fp16x2 h; _Float16 e[2]; unsigned int u; };

__device__ __forceinline__ float fast_tanh(float z) {
    float e = __expf(2.0f * z);
    return 1.0f - 2.0f * __builtin_amdgcn_rcpf(e + 1.0f);
}

__device__ __forceinline__ unsigned int pk2(float a, float b) {
    H2 r; r.h = __builtin_amdgcn_cvt_pkrtz(a, b);
    return r.u;
}

// ---------------------------------------------------------------------------
// Pack weights into MFMA A-fragment order (fp16 hi+lo).  (unchanged r9)
// W1..W3: hi at wsU + l*32768, lo at +16384. V1-hi at wsU+98304.
// W4 padded 128x16: hi at wsU+102400, lo +2048. Block 24 zeroes out[0].
// ---------------------------------------------------------------------------
__global__ __launch_bounds__(256) void pack_w_kernel(
    const float* __restrict__ W1, const float* __restrict__ W2,
    const float* __restrict__ W3, const float* __restrict__ V1,
    const float* __restrict__ W4,
    unsigned short* __restrict__ wsU, float* __restrict__ out)
{
    int b = blockIdx.x;
    if (b < 24) {
        int mat = b >> 3, rb = b & 7;          // 16 rows per block
        const float* W = (mat == 0) ? W1 : (mat == 1) ? W2 : W3;
        unsigned int* hiU = (unsigned int*)(wsU + mat * 32768);
        unsigned int* loU = hiU + 8192;
        int n   = threadIdx.x & 127;
        int pr0 = threadIdx.x >> 7;
        #pragma unroll
        for (int it = 0; it < 4; it++) {
            int pr = pr0 + 2 * it;
            int k  = rb * 16 + pr * 2;
            float v0 = W[k * 128 + n];
            float v1 = W[(k + 1) * 128 + n];
            H2 hh, ll;
            hh.e[0] = (_Float16)v0;
            hh.e[1] = (_Float16)v1;
            ll.e[0] = (_Float16)(v0 - (float)hh.e[0]);
            ll.e[1] = (_Float16)(v1 - (float)hh.e[1]);
            int base = ((n >> 4) * 4 + (k >> 5)) * 64 + ((k >> 3) & 3) * 16 + (n & 15);
            int uoff = base * 4 + ((k & 7) >> 1);
            hiU[uoff] = hh.u;
            loU[uoff] = ll.u;
        }
    } else if (b == 24) {
        unsigned int* hiU = (unsigned int*)(wsU + 98304);
        int n   = threadIdx.x & 63;
        int pr0 = threadIdx.x >> 6;
        #pragma unroll
        for (int it = 0; it < 8; it++) {
            int pr = pr0 + 4 * it;
            int k  = pr * 2;
            float v0 = V1[k * 64 + n];
            float v1 = V1[(k + 1) * 64 + n];
            H2 hh;
            hh.e[0] = (_Float16)v0;
            hh.e[1] = (_Float16)v1;
            int base = ((n >> 4) * 2 + (k >> 5)) * 64 + ((k >> 3) & 3) * 16 + (n & 15);
            hiU[base * 4 + ((k & 7) >> 1)] = hh.u;
        }
        if (threadIdx.x == 0) out[0] = 0.f;
    } else {
        _Float16* hi = (_Float16*)(wsU + 102400);
        _Float16* lo = hi + 2048;
        int u4 = threadIdx.x;
        int lane = u4 & 63, ks = u4 >> 6;
        int m  = lane & 15;
        int kb = ks * 32 + ((lane >> 4) << 3);
        FragU fh, fl;
        #pragma unroll
        for (int j = 0; j < 8; j++) {
            float v = (m < 4) ? W4[(kb + j) * 4 + m] : 0.f;
            _Float16 h = (_Float16)v;
            fh.e[j] = h;
            fl.e[j] = (_Float16)(v - (float)h);
        }
        *(uint4*)(hi + u4 * 8) = fh.q;
        *(uint4*)(lo + u4 * 8) = fl.q;
    }
}

// ---------------------------------------------------------------------------
// Fused kernel. Blocks [0,256): boundary (64 pts). Blocks [256,2304):
// physics (16 pts, 4 AD streams: 0=value 1=d/dx 2=d/dy 3=Laplacian).
// Identical to r15 except for the block-order flip.
// ---------------------------------------------------------------------------
__global__ __launch_bounds__(256, 5) void fused_kernel(
    const float* __restrict__ xt,
    const float* __restrict__ x_inlet, const float* __restrict__ U_inlet,
    const float* __restrict__ x_base,  const float* __restrict__ x_top,
    const float* __restrict__ x_slip,
    const float* __restrict__ W0, const float* __restrict__ b0,
    const float* __restrict__ W1, const float* __restrict__ b1,
    const float* __restrict__ W2, const float* __restrict__ b2,
    const float* __restrict__ W3, const float* __restrict__ b3,
    const float* __restrict__ W4, const float* __restrict__ b4,
    const float* __restrict__ V0, const float* __restrict__ c0,
    const float* __restrict__ V1, const float* __restrict__ c1,
    const float* __restrict__ V2, const float* __restrict__ c2,
    const unsigned short* __restrict__ wsU,
    float* __restrict__ out)
{
    __shared__ float SM[5056];   // 20,224 B -> 8 blocks/CU
    const int t = threadIdx.x;
    const int wv   = t >> 6;
    const int lane = t & 63;
    const int nn   = lane & 15;
    const int q    = lane >> 4;

    if (blockIdx.x >= BDY_BLOCKS) {
        // =================== PHYSICS PATH (16 pts) ===================
        const int pb = blockIdx.x - BDY_BLOCKS;   // physics block 0..2047
        unsigned short* AhU = (unsigned short*)SM;   // 64 rows x 136 ushorts
        float* OUTF   = SM + 4352;   // 64 x 4
        float* MUPART = SM + 4608;   // 64 (wave-major mu partials)
        float* BIASF  = SM + 4672;   // b1|b2|b3 (384 floats)

        const int p = t >> 4;   // point 0..15
        const int c = t & 15;

        const int ptIdx = pb * 16 + p;
        const float2 xy = *(const float2*)(xt + ptIdx * 2);
        const float x = xy.x, y = xy.y;

        // ---- phase 0: biases + register-mu (L1+L2+L3 partial) + layer 0 ---
        if (t < 128) {
            BIASF[t]       = b1[t];
            BIASF[128 + t] = b2[t];
            BIASF[256 + t] = b3[t];
        }
        {
            // mu-L1 in registers: lane (nn,q) computes units ks*32+q*8+j of
            // point nn -> exactly the mu-L2 MFMA B-fragment.
            const float2 xyn = *(const float2*)(xt + (pb * 16 + nn) * 2);
            FragU mb[2];
            #pragma unroll
            for (int ks = 0; ks < 2; ks++) {
                int u0 = ks * 32 + q * 8;
                F4 va0, va1, vb0, vb1, cc0, cc1;
                va0.v = *(const float4*)(V0 + u0);
                va1.v = *(const float4*)(V0 + u0 + 4);
                vb0.v = *(const float4*)(V0 + 64 + u0);
                vb1.v = *(const float4*)(V0 + 64 + u0 + 4);
                cc0.v = *(const float4*)(c0 + u0);
                cc1.v = *(const float4*)(c0 + u0 + 4);
                #pragma unroll
                for (int i = 0; i < 4; i++) {
                    mb[ks].e[i]     = (_Float16)fast_tanh(
                        xyn.x * va0.f[i] + xyn.y * vb0.f[i] + cc0.f[i]);
                    mb[ks].e[4 + i] = (_Float16)fast_tanh(
                        xyn.x * va1.f[i] + xyn.y * vb1.f[i] + cc1.f[i]);
                }
            }
            // mu-L2 MFMA: wave wv -> output units wv*16 + q*4 + r, point nn
            f32x4 macc = {0.f, 0.f, 0.f, 0.f};
            #pragma unroll
            for (int ks = 0; ks < 2; ks++) {
                FragU vh;
                vh.q = *(const uint4*)(wsU + 98304 + (((wv * 2 + ks) * 64 + lane) << 3));
                macc = __builtin_amdgcn_mfma_f32_16x16x32_f16(vh.b, mb[ks].b, macc, 0, 0, 0);
            }
            int u2 = wv * 16 + q * 4;
            F4 cv, w2;
            cv.v = *(const float4*)(c1 + u2);
            w2.v = *(const float4*)(V2 + u2);
            float partial = 0.f;
            #pragma unroll
            for (int r = 0; r < 4; r++)
                partial += fast_tanh(macc[r] + cv.f[r]) * w2.f[r];
            partial += __shfl_xor(partial, 16);
            partial += __shfl_xor(partial, 32);
            if (lane < 16) MUPART[wv * 16 + nn] = partial;
        }
        {   // main layer 0: 2 -> 128, 4 streams
            float vals[4][8];
            #pragma unroll
            for (int j = 0; j < 8; j++) {
                int u = c * 8 + j;
                float w0 = W0[u], w1 = W0[128 + u];
                float zv = x * w0 + y * w1 + b0[u];
                float tt = fast_tanh(zv);
                float s2 = 1.f - tt * tt;
                float m2 = -2.f * tt * s2;
                vals[0][j] = tt;
                vals[1][j] = s2 * w0;
                vals[2][j] = s2 * w1;
                vals[3][j] = m2 * (w0 * w0 + w1 * w1);  // z_lap = 0 at layer 0
            }
            #pragma unroll
            for (int s = 0; s < 4; s++) {
                uint4 d = make_uint4(pk2(vals[s][0], vals[s][1]),
                                     pk2(vals[s][2], vals[s][3]),
                                     pk2(vals[s][4], vals[s][5]),
                                     pk2(vals[s][6], vals[s][7]));
                *(uint4*)(AhU + (s * 16 + p) * 136 + c * 8) = d;
            }
        }
        __syncthreads();

        // ------- hidden layers 1..3 via MFMA (value 2-pass, derivs 1) ------
        #pragma unroll 1
        for (int l = 0; l < 3; l++) {
            const unsigned short* WpL = wsU + l * 32768;
            f32x4 acc[2][4];
            #pragma unroll
            for (int i = 0; i < 2; i++)
                #pragma unroll
                for (int s = 0; s < 4; s++) {
                    acc[i][s][0] = 0.f; acc[i][s][1] = 0.f;
                    acc[i][s][2] = 0.f; acc[i][s][3] = 0.f;
                }
            #pragma unroll
            for (int ks = 0; ks < 4; ks++) {
                FragU bh[4];
                #pragma unroll
                for (int s = 0; s < 4; s++)
                    bh[s].q = *(const uint4*)(AhU + (s * 16 + nn) * 136 + ks * 32 + q * 8);
                FragU wh[2], wl[2];
                #pragma unroll
                for (int i = 0; i < 2; i++) {
                    const unsigned short* base =
                        WpL + ((((2 * wv + i) * 4 + ks) * 64 + lane) << 3);
                    wh[i].q = *(const uint4*)base;
                    wl[i].q = *(const uint4*)(base + 16384);
                }
                #pragma unroll
                for (int i = 0; i < 2; i++) {
                    acc[i][0] = __builtin_amdgcn_mfma_f32_16x16x32_f16(
                        wh[i].b, bh[0].b, acc[i][0], 0, 0, 0);
                    acc[i][0] = __builtin_amdgcn_mfma_f32_16x16x32_f16(
                        wl[i].b, bh[0].b, acc[i][0], 0, 0, 0);
                    #pragma unroll
                    for (int s = 1; s < 4; s++)
                        acc[i][s] = __builtin_amdgcn_mfma_f32_16x16x32_f16(
                            wh[i].b, bh[s].b, acc[i][s], 0, 0, 0);
                }
            }
            __syncthreads();   // all A reads done before overwrite
            #pragma unroll
            for (int i = 0; i < 2; i++) {
                int ubase = (2 * wv + i) * 16 + q * 4;
                F4 bv; bv.v = *(const float4*)&BIASF[l * 128 + ubase];
                float vals[4][4];
                #pragma unroll
                for (int r = 0; r < 4; r++) {
                    float z  = acc[i][0][r] + bv.f[r];
                    float zx = acc[i][1][r], zy = acc[i][2][r];
                    float zl = acc[i][3][r];
                    float tt = fast_tanh(z);
                    float s2 = 1.f - tt * tt;
                    float m2 = -2.f * tt * s2;
                    vals[0][r] = tt;
                    vals[1][r] = s2 * zx;
                    vals[2][r] = s2 * zy;
                    vals[3][r] = s2 * zl + m2 * (zx * zx + zy * zy);
                }
                #pragma unroll
                for (int s = 0; s < 4; s++) {
                    uint2 d = make_uint2(pk2(vals[s][0], vals[s][1]),
                                         pk2(vals[s][2], vals[s][3]));
                    *(uint2*)(AhU + (s * 16 + nn) * 136 + ubase) = d;
                }
            }
            __syncthreads();
        }

        // ---------------- layer 4: 128 -> 4 via MFMA (padded W4) -----------
        {
            const unsigned short* W4p = wsU + 102400;
            f32x4 a4 = {0.f, 0.f, 0.f, 0.f};
            #pragma unroll
            for (int ks = 0; ks < 4; ks++) {
                FragU bh, wh, wl;
                bh.q = *(const uint4*)(AhU + (wv * 16 + nn) * 136 + ks * 32 + q * 8);
                const unsigned short* base = W4p + ((ks * 64 + lane) << 3);
                wh.q = *(const uint4*)base;
                wl.q = *(const uint4*)(base + 2048);
                a4 = __builtin_amdgcn_mfma_f32_16x16x32_f16(wh.b, bh.b, a4, 0, 0, 0);
                a4 = __builtin_amdgcn_mfma_f32_16x16x32_f16(wl.b, bh.b, a4, 0, 0, 0);
            }
            if (q == 0) {
                float4 o = make_float4(a4[0], a4[1], a4[2], a4[3]);
                if (wv == 0) {   // value stream gets bias
                    o.x += b4[0]; o.y += b4[1]; o.z += b4[2]; o.w += b4[3];
                }
                *(float4*)&OUTF[(wv * 16 + nn) * 4] = o;
            }
        }
        __syncthreads();

        // ---------------- per-point residual + reduction -------------------
        float contrib = 0.f;
        if (t < 16) {
            const int pp = t;
            const float* V   = &OUTF[(0  + pp) * 4];
            const float* DX  = &OUTF[(16 + pp) * 4];
            const float* DY  = &OUTF[(32 + pp) * 4];
            const float* LAP = &OUTF[(48 + pp) * 4];
            float r = V[0],  P = V[1],  u = V[2],  v = V[3];
            float rx = DX[0], Px = DX[1], ux = DX[2], vx = DX[3];
            float ry = DY[0], Py = DY[1], uy = DY[2], vy = DY[3];
            float rl = LAP[0], Pl = LAP[1], ul = LAP[2], vl = LAP[3];
            const float GI = 2.5f;  // 1/(gamma-1)

            float s = MUPART[pp] + MUPART[16 + pp] + MUPART[32 + pp]
                    + MUPART[48 + pp] + c2[0];
            float mu = 0.01f * s * s;

            float q2 = u * u + v * v;
            float E  = P * GI + 0.5f * r * q2;
            float Ex = Px * GI + 0.5f * rx * q2 + r * (u * ux + v * vx);
            float Ey = Py * GI + 0.5f * ry * q2 + r * (u * uy + v * vy);
            float EpP = E + P;

            float f1x = rx * u + r * ux;
            float f2x = rx * u * u + 2.f * r * u * ux + Px;
            float f3x = rx * u * v + r * ux * v + r * u * vx;
            float f4x = ux * EpP + u * (Ex + Px);

            float g1y = ry * v + r * vy;
            float g2y = ry * u * v + r * uy * v + r * u * vy;
            float g3y = ry * v * v + 2.f * r * v * vy + Py;
            float g4y = vy * EpP + v * (Ey + Py);

            float qx  = 2.f * (u * ux + v * vx);
            float qy  = 2.f * (u * uy + v * vy);
            float ql  = 2.f * (ux * ux + uy * uy + vx * vx + vy * vy)
                      + 2.f * (u * ul + v * vl);

            float U1s = rl;
            float U2s = rl * u + 2.f * (rx * ux + ry * uy) + r * ul;
            float U3s = rl * v + 2.f * (rx * vx + ry * vy) + r * vl;
            float U4s = Pl * GI
                      + 0.5f * (rl * q2 + 2.f * (rx * qx + ry * qy) + r * ql);

            float r1 = f1x + g1y - mu * U1s;
            float r2 = f2x + g2y - mu * U2s;
            float r3 = f3x + g3y - mu * U3s;
            float r4 = f4x + g4y - mu * U4s;

            contrib = (r1 * r1 + r2 * r2 + r3 * r3 + r4 * r4 + 0.1f * mu * mu)
                      * (1.0f / (float)NTRAIN);
        }
        if (t < 64) {
            contrib += __shfl_down(contrib, 32);
            contrib += __shfl_down(contrib, 16);
            contrib += __shfl_down(contrib, 8);
            contrib += __shfl_down(contrib, 4);
            contrib += __shfl_down(contrib, 2);
            contrib += __shfl_down(contrib, 1);
            if (t == 0) atomicAdd(out, contrib);
        }
    } else {
        // =================== BOUNDARY PATH (MFMA, 64 pts/block) ============
        unsigned short* ShU = (unsigned short*)SM;   // 64 x 136
        float* OUTB  = SM + 4352;   // 64 x 4
        float* BIASB = SM + 4608;   // 384 floats

        const int bb    = blockIdx.x;
        const int batch = bb >> 6;  // 0..3 (64 blocks each)
        const int lb    = bb & 63;
        const float* xs = (batch == 0) ? x_inlet
                        : (batch == 1) ? x_base
                        : (batch == 2) ? x_top : x_slip;
        const int base_pt = lb * 64;

        // ---- layer 0: 2 -> 128 (4 threads/pt, 32 units each) + biases ----
        {
            int p2 = t & 63, ug = t >> 6;
            float2 xy = *(const float2*)(xs + (base_pt + p2) * 2);
            float x = xy.x, y = xy.y;
            #pragma unroll
            for (int g = 0; g < 8; g++) {
                int u0 = ug * 32 + g * 4;
                F4 wa, wb, bbv;
                wa.v  = *(const float4*)(W0 + u0);
                wb.v  = *(const float4*)(W0 + 128 + u0);
                bbv.v = *(const float4*)(b0 + u0);
                float t0 = fast_tanh(x * wa.f[0] + y * wb.f[0] + bbv.f[0]);
                float t1 = fast_tanh(x * wa.f[1] + y * wb.f[1] + bbv.f[1]);
                float t2 = fast_tanh(x * wa.f[2] + y * wb.f[2] + bbv.f[2]);
                float t3 = fast_tanh(x * wa.f[3] + y * wb.f[3] + bbv.f[3]);
                uint2 d = make_uint2(pk2(t0, t1), pk2(t2, t3));
                *(uint2*)(ShU + p2 * 136 + u0) = d;
            }
            if (t < 128) {
                BIASB[t]       = b1[t];
                BIASB[128 + t] = b2[t];
                BIASB[256 + t] = b3[t];
            }
        }
        __syncthreads();

        // ---- hidden layers 1..3 via MFMA (W hi only, 4 point-tiles) ----
        #pragma unroll 1
        for (int l = 0; l < 3; l++) {
            const unsigned short* WpL = wsU + l * 32768;
            f32x4 acc[2][4];
            #pragma unroll
            for (int i = 0; i < 2; i++)
                #pragma unroll
                for (int n = 0; n < 4; n++) {
                    acc[i][n][0] = 0.f; acc[i][n][1] = 0.f;
                    acc[i][n][2] = 0.f; acc[i][n][3] = 0.f;
                }
            #pragma unroll
            for (int ks = 0; ks < 4; ks++) {
                FragU bh[4];
                #pragma unroll
                for (int n = 0; n < 4; n++)
                    bh[n].q = *(const uint4*)(ShU + (n * 16 + nn) * 136 + ks * 32 + q * 8);
                FragU wh[2];
                #pragma unroll
                for (int i = 0; i < 2; i++)
                    wh[i].q = *(const uint4*)(WpL + ((((2 * wv + i) * 4 + ks) * 64 + lane) << 3));
                #pragma unroll
                for (int i = 0; i < 2; i++)
                    #pragma unroll
                    for (int n = 0; n < 4; n++)
                        acc[i][n] = __builtin_amdgcn_mfma_f32_16x16x32_f16(
                            wh[i].b, bh[n].b, acc[i][n], 0, 0, 0);
            }
            __syncthreads();
            #pragma unroll
            for (int i = 0; i < 2; i++) {
                int ubase = (2 * wv + i) * 16 + q * 4;
                F4 bv; bv.v = *(const float4*)&BIASB[l * 128 + ubase];
                #pragma unroll
                for (int n = 0; n < 4; n++) {
                    float t0 = fast_tanh(acc[i][n][0] + bv.f[0]);
                    float t1 = fast_tanh(acc[i][n][1] + bv.f[1]);
                    float t2 = fast_tanh(acc[i][n][2] + bv.f[2]);
                    float t3 = fast_tanh(acc[i][n][3] + bv.f[3]);
                    uint2 d = make_uint2(pk2(t0, t1), pk2(t2, t3));
                    *(uint2*)(ShU + (n * 16 + nn) * 136 + ubase) = d;
                }
            }
            __syncthreads();
        }

        // ---- layer 4 via MFMA (padded W4, hi+lo), one point-tile/wave ----
        {
            const unsigned short* W4p = wsU + 102400;
            f32x4 a4 = {0.f, 0.f, 0.f, 0.f};
            #pragma unroll
            for (int ks = 0; ks < 4; ks++) {
                FragU bh, wh, wl;
                bh.q = *(const uint4*)(ShU + (wv * 16 + nn) * 136 + ks * 32 + q * 8);
                const unsigned short* base = W4p + ((ks * 64 + lane) << 3);
                wh.q = *(const uint4*)base;
                wl.q = *(const uint4*)(base + 2048);
                a4 = __builtin_amdgcn_mfma_f32_16x16x32_f16(wh.b, bh.b, a4, 0, 0, 0);
                a4 = __builtin_amdgcn_mfma_f32_16x16x32_f16(wl.b, bh.b, a4, 0, 0, 0);
            }
            if (q == 0) {
                float4 o = make_float4(a4[0] + b4[0], a4[1] + b4[1],
                                       a4[2] + b4[2], a4[3] + b4[3]);
                *(float4*)&OUTB[(wv * 16 + nn) * 4] = o;
            }
        }
        __syncthreads();

        float contrib = 0.f;
        if (t < 64) {
            float o0 = OUTB[t * 4 + 0], o1 = OUTB[t * 4 + 1];
            float o2 = OUTB[t * 4 + 2], o3 = OUTB[t * 4 + 3];
            float l;
            if (batch == 0) {
                float4 Ui = *(const float4*)(U_inlet + (base_pt + t) * 4);
                float d0 = o0 - Ui.x, d1 = o1 - Ui.y, d2 = o2 - Ui.z, d3 = o3 - Ui.w;
                l = d0 * d0 + d1 * d1 + d2 * d2 + d3 * d3;
            } else if (batch == 3) {
                const float sa = -0.17364817766693033f;  // sin(-pi/18)
                const float ca =  0.9848077530122080f;   // cos(-pi/18)
                float d = -o2 * sa + o3 * ca;
                l = d * d;
            } else {
                l = o3 * o3;
            }
            contrib = 10.0f * l * (1.0f / (float)NBDY);
        }
        if (t < 64) {
            contrib += __shfl_down(contrib, 32);
            contrib += __shfl_down(contrib, 16);
            contrib += __shfl_down(contrib, 8);
            contrib += __shfl_down(contrib, 4);
            contrib += __shfl_down(contrib, 2);
            contrib += __shfl_down(contrib, 1);
            if (t == 0) atomicAdd(out, contrib);
        }
    }
}

extern "C" void kernel_launch(void* const* d_in, const int* in_sizes, int n_in,
                              void* d_out, int out_size, void* d_ws, size_t ws_size,
                              hipStream_t stream) {
    const float* xt      = (const float*)d_in[0];
    const float* x_inlet = (const float*)d_in[1];
    const float* U_inlet = (const float*)d_in[2];
    const float* x_base  = (const float*)d_in[3];
    const float* x_top   = (const float*)d_in[4];
    const float* x_slip  = (const float*)d_in[5];
    const float* W0 = (const float*)d_in[6];
    const float* b0 = (const float*)d_in[7];
    const float* W1 = (const float*)d_in[8];
    const float* b1 = (const float*)d_in[9];
    const float* W2 = (const float*)d_in[10];
    const float* b2 = (const float*)d_in[11];
    const float* W3 = (const float*)d_in[12];
    const float* b3 = (const float*)d_in[13];
    const float* W4 = (const float*)d_in[14];
    const float* b4 = (const float*)d_in[15];
    const float* V0 = (const float*)d_in[16];
    const float* c0 = (const float*)d_in[17];
    const float* V1 = (const float*)d_in[18];
    const float* c1 = (const float*)d_in[19];
    const float* V2 = (const float*)d_in[20];
    const float* c2 = (const float*)d_in[21];
    float* out = (float*)d_out;
    unsigned short* wsU = (unsigned short*)d_ws;

    pack_w_kernel<<<26, 256, 0, stream>>>(W1, W2, W3, V1, W4, wsU, out);

    fused_kernel<<<PHYS_BLOCKS + BDY_BLOCKS, 256, 0, stream>>>(
        xt, x_inlet, U_inlet, x_base, x_top, x_slip,
        W0, b0, W1, b1, W2, b2, W3, b3, W4, b4,
        V0, c0, V1, c1, V2, c2, wsU, out);
}

// Round 17
// 136.264 us; speedup vs baseline: 1.0175x; 1.0175x over previous
//
#include <hip/hip_runtime.h>

#define NTRAIN 32768
#define NBDY   4096
#define PHYS_BLOCKS (NTRAIN / 16)   // 2048 blocks, 16 pts each
#define BDY_BLOCKS  256             // 64 pts/block, 64 blocks per batch

typedef _Float16 f16x8 __attribute__((ext_vector_type(8)));
typedef __fp16   fp16x2 __attribute__((ext_vector_type(2)));
typedef float    f32x4 __attribute__((ext_vector_type(4)));

union FragU { uint4 q; f16x8 b; _Float16 e[8]; };
union F4  { float4 v; float f[4]; };
union U2h { _Float16 e[4]; uint2 d; };
union H2  { fp16x2 h; _Float16 e[2]; unsigned int u; };

__device__ __forceinline__ float fast_tanh(float z) {
    float e = __expf(2.0f * z);
    return 1.0f - 2.0f * __builtin_amdgcn_rcpf(e + 1.0f);
}

__device__ __forceinline__ unsigned int pk2(float a, float b) {
    H2 r; r.h = __builtin_amdgcn_cvt_pkrtz(a, b);
    return r.u;
}

// ---------------------------------------------------------------------------
// Pack weights into MFMA A-fragment order (fp16 hi+lo).  (unchanged r9)
// W1..W3: hi at wsU + l*32768, lo at +16384 (lo now used only by nothing in
// the fused kernel's hidden layers; kept for W4-style safety/simplicity).
// V1-hi at wsU+98304. W4 padded 128x16: hi at wsU+102400, lo +2048.
// Block 24 zeroes out[0].
// ---------------------------------------------------------------------------
__global__ __launch_bounds__(256) void pack_w_kernel(
    const float* __restrict__ W1, const float* __restrict__ W2,
    const float* __restrict__ W3, const float* __restrict__ V1,
    const float* __restrict__ W4,
    unsigned short* __restrict__ wsU, float* __restrict__ out)
{
    int b = blockIdx.x;
    if (b < 24) {
        int mat = b >> 3, rb = b & 7;          // 16 rows per block
        const float* W = (mat == 0) ? W1 : (mat == 1) ? W2 : W3;
        unsigned int* hiU = (unsigned int*)(wsU + mat * 32768);
        unsigned int* loU = hiU + 8192;
        int n   = threadIdx.x & 127;
        int pr0 = threadIdx.x >> 7;
        #pragma unroll
        for (int it = 0; it < 4; it++) {
            int pr = pr0 + 2 * it;
            int k  = rb * 16 + pr * 2;
            float v0 = W[k * 128 + n];
            float v1 = W[(k + 1) * 128 + n];
            H2 hh, ll;
            hh.e[0] = (_Float16)v0;
            hh.e[1] = (_Float16)v1;
            ll.e[0] = (_Float16)(v0 - (float)hh.e[0]);
            ll.e[1] = (_Float16)(v1 - (float)hh.e[1]);
            int base = ((n >> 4) * 4 + (k >> 5)) * 64 + ((k >> 3) & 3) * 16 + (n & 15);
            int uoff = base * 4 + ((k & 7) >> 1);
            hiU[uoff] = hh.u;
            loU[uoff] = ll.u;
        }
    } else if (b == 24) {
        unsigned int* hiU = (unsigned int*)(wsU + 98304);
        int n   = threadIdx.x & 63;
        int pr0 = threadIdx.x >> 6;
        #pragma unroll
        for (int it = 0; it < 8; it++) {
            int pr = pr0 + 4 * it;
            int k  = pr * 2;
            float v0 = V1[k * 64 + n];
            float v1 = V1[(k + 1) * 64 + n];
            H2 hh;
            hh.e[0] = (_Float16)v0;
            hh.e[1] = (_Float16)v1;
            int base = ((n >> 4) * 2 + (k >> 5)) * 64 + ((k >> 3) & 3) * 16 + (n & 15);
            hiU[base * 4 + ((k & 7) >> 1)] = hh.u;
        }
        if (threadIdx.x == 0) out[0] = 0.f;
    } else {
        _Float16* hi = (_Float16*)(wsU + 102400);
        _Float16* lo = hi + 2048;
        int u4 = threadIdx.x;
        int lane = u4 & 63, ks = u4 >> 6;
        int m  = lane & 15;
        int kb = ks * 32 + ((lane >> 4) << 3);
        FragU fh, fl;
        #pragma unroll
        for (int j = 0; j < 8; j++) {
            float v = (m < 4) ? W4[(kb + j) * 4 + m] : 0.f;
            _Float16 h = (_Float16)v;
            fh.e[j] = h;
            fl.e[j] = (_Float16)(v - (float)h);
        }
        *(uint4*)(hi + u4 * 8) = fh.q;
        *(uint4*)(lo + u4 * 8) = fl.q;
    }
}

// ---------------------------------------------------------------------------
// Fused kernel. Blocks [0,2048): physics (16 pts, 4 AD streams:
// 0=value 1=d/dx 2=d/dy 3=Laplacian). Blocks [2048,2304): boundary (64 pts).
//
// r17 = r15 (best: 48.9 us kernel) with the hidden layers' value stream
// dropped to 1-pass fp16 W (was hi+lo 2-pass): ~6e-4 relative W rounding,
// ~0.3% on outputs, far under the 2% loss threshold (absmax has been 0.00
// all session). Hidden-layer MFMA count -20%, wl loads removed from K-loop.
// Layer 4 keeps hi+lo. launch_bounds(256,5) = 102-VGPR budget (r15).
// ---------------------------------------------------------------------------
__global__ __launch_bounds__(256, 5) void fused_kernel(
    const float* __restrict__ xt,
    const float* __restrict__ x_inlet, const float* __restrict__ U_inlet,
    const float* __restrict__ x_base,  const float* __restrict__ x_top,
    const float* __restrict__ x_slip,
    const float* __restrict__ W0, const float* __restrict__ b0,
    const float* __restrict__ W1, const float* __restrict__ b1,
    const float* __restrict__ W2, const float* __restrict__ b2,
    const float* __restrict__ W3, const float* __restrict__ b3,
    const float* __restrict__ W4, const float* __restrict__ b4,
    const float* __restrict__ V0, const float* __restrict__ c0,
    const float* __restrict__ V1, const float* __restrict__ c1,
    const float* __restrict__ V2, const float* __restrict__ c2,
    const unsigned short* __restrict__ wsU,
    float* __restrict__ out)
{
    __shared__ float SM[5056];   // 20,224 B
    const int t = threadIdx.x;
    const int wv   = t >> 6;
    const int lane = t & 63;
    const int nn   = lane & 15;
    const int q    = lane >> 4;

    if (blockIdx.x < PHYS_BLOCKS) {
        // =================== PHYSICS PATH (16 pts) ===================
        unsigned short* AhU = (unsigned short*)SM;   // 64 rows x 136 ushorts
        float* OUTF   = SM + 4352;   // 64 x 4
        float* MUPART = SM + 4608;   // 64 (wave-major mu partials)
        float* BIASF  = SM + 4672;   // b1|b2|b3 (384 floats)

        const int p = t >> 4;   // point 0..15
        const int c = t & 15;

        const int ptIdx = blockIdx.x * 16 + p;
        const float2 xy = *(const float2*)(xt + ptIdx * 2);
        const float x = xy.x, y = xy.y;

        // ---- phase 0: biases + register-mu (L1+L2+L3 partial) + layer 0 ---
        if (t < 128) {
            BIASF[t]       = b1[t];
            BIASF[128 + t] = b2[t];
            BIASF[256 + t] = b3[t];
        }
        {
            // mu-L1 in registers: lane (nn,q) computes units ks*32+q*8+j of
            // point nn -> exactly the mu-L2 MFMA B-fragment.
            const float2 xyn = *(const float2*)(xt + (blockIdx.x * 16 + nn) * 2);
            FragU mb[2];
            #pragma unroll
            for (int ks = 0; ks < 2; ks++) {
                int u0 = ks * 32 + q * 8;
                F4 va0, va1, vb0, vb1, cc0, cc1;
                va0.v = *(const float4*)(V0 + u0);
                va1.v = *(const float4*)(V0 + u0 + 4);
                vb0.v = *(const float4*)(V0 + 64 + u0);
                vb1.v = *(const float4*)(V0 + 64 + u0 + 4);
                cc0.v = *(const float4*)(c0 + u0);
                cc1.v = *(const float4*)(c0 + u0 + 4);
                #pragma unroll
                for (int i = 0; i < 4; i++) {
                    mb[ks].e[i]     = (_Float16)fast_tanh(
                        xyn.x * va0.f[i] + xyn.y * vb0.f[i] + cc0.f[i]);
                    mb[ks].e[4 + i] = (_Float16)fast_tanh(
                        xyn.x * va1.f[i] + xyn.y * vb1.f[i] + cc1.f[i]);
                }
            }
            // mu-L2 MFMA: wave wv -> output units wv*16 + q*4 + r, point nn
            f32x4 macc = {0.f, 0.f, 0.f, 0.f};
            #pragma unroll
            for (int ks = 0; ks < 2; ks++) {
                FragU vh;
                vh.q = *(const uint4*)(wsU + 98304 + (((wv * 2 + ks) * 64 + lane) << 3));
                macc = __builtin_amdgcn_mfma_f32_16x16x32_f16(vh.b, mb[ks].b, macc, 0, 0, 0);
            }
            int u2 = wv * 16 + q * 4;
            F4 cv, w2;
            cv.v = *(const float4*)(c1 + u2);
            w2.v = *(const float4*)(V2 + u2);
            float partial = 0.f;
            #pragma unroll
            for (int r = 0; r < 4; r++)
                partial += fast_tanh(macc[r] + cv.f[r]) * w2.f[r];
            partial += __shfl_xor(partial, 16);
            partial += __shfl_xor(partial, 32);
            if (lane < 16) MUPART[wv * 16 + nn] = partial;
        }
        {   // main layer 0: 2 -> 128, 4 streams
            float vals[4][8];
            #pragma unroll
            for (int j = 0; j < 8; j++) {
                int u = c * 8 + j;
                float w0 = W0[u], w1 = W0[128 + u];
                float zv = x * w0 + y * w1 + b0[u];
                float tt = fast_tanh(zv);
                float s2 = 1.f - tt * tt;
                float m2 = -2.f * tt * s2;
                vals[0][j] = tt;
                vals[1][j] = s2 * w0;
                vals[2][j] = s2 * w1;
                vals[3][j] = m2 * (w0 * w0 + w1 * w1);  // z_lap = 0 at layer 0
            }
            #pragma unroll
            for (int s = 0; s < 4; s++) {
                uint4 d = make_uint4(pk2(vals[s][0], vals[s][1]),
                                     pk2(vals[s][2], vals[s][3]),
                                     pk2(vals[s][4], vals[s][5]),
                                     pk2(vals[s][6], vals[s][7]));
                *(uint4*)(AhU + (s * 16 + p) * 136 + c * 8) = d;
            }
        }
        __syncthreads();

        // ------- hidden layers 1..3 via MFMA (all streams 1-pass W-hi) -----
        #pragma unroll 1
        for (int l = 0; l < 3; l++) {
            const unsigned short* WpL = wsU + l * 32768;
            f32x4 acc[2][4];
            #pragma unroll
            for (int i = 0; i < 2; i++)
                #pragma unroll
                for (int s = 0; s < 4; s++) {
                    acc[i][s][0] = 0.f; acc[i][s][1] = 0.f;
                    acc[i][s][2] = 0.f; acc[i][s][3] = 0.f;
                }
            #pragma unroll
            for (int ks = 0; ks < 4; ks++) {
                FragU bh[4];
                #pragma unroll
                for (int s = 0; s < 4; s++)
                    bh[s].q = *(const uint4*)(AhU + (s * 16 + nn) * 136 + ks * 32 + q * 8);
                FragU wh[2];
                #pragma unroll
                for (int i = 0; i < 2; i++)
                    wh[i].q = *(const uint4*)(WpL + ((((2 * wv + i) * 4 + ks) * 64 + lane) << 3));
                #pragma unroll
                for (int i = 0; i < 2; i++)
                    #pragma unroll
                    for (int s = 0; s < 4; s++)
                        acc[i][s] = __builtin_amdgcn_mfma_f32_16x16x32_f16(
                            wh[i].b, bh[s].b, acc[i][s], 0, 0, 0);
            }
            __syncthreads();   // all A reads done before overwrite
            #pragma unroll
            for (int i = 0; i < 2; i++) {
                int ubase = (2 * wv + i) * 16 + q * 4;
                F4 bv; bv.v = *(const float4*)&BIASF[l * 128 + ubase];
                float vals[4][4];
                #pragma unroll
                for (int r = 0; r < 4; r++) {
                    float z  = acc[i][0][r] + bv.f[r];
                    float zx = acc[i][1][r], zy = acc[i][2][r];
                    float zl = acc[i][3][r];
                    float tt = fast_tanh(z);
                    float s2 = 1.f - tt * tt;
                    float m2 = -2.f * tt * s2;
                    vals[0][r] = tt;
                    vals[1][r] = s2 * zx;
                    vals[2][r] = s2 * zy;
                    vals[3][r] = s2 * zl + m2 * (zx * zx + zy * zy);
                }
                #pragma unroll
                for (int s = 0; s < 4; s++) {
                    uint2 d = make_uint2(pk2(vals[s][0], vals[s][1]),
                                         pk2(vals[s][2], vals[s][3]));
                    *(uint2*)(AhU + (s * 16 + nn) * 136 + ubase) = d;
                }
            }
            __syncthreads();
        }

        // ---------------- layer 4: 128 -> 4 via MFMA (padded W4, hi+lo) ----
        {
            const unsigned short* W4p = wsU + 102400;
            f32x4 a4 = {0.f, 0.f, 0.f, 0.f};
            #pragma unroll
            for (int ks = 0; ks < 4; ks++) {
                FragU bh, wh, wl;
                bh.q = *(const uint4*)(AhU + (wv * 16 + nn) * 136 + ks * 32 + q * 8);
                const unsigned short* base = W4p + ((ks * 64 + lane) << 3);
                wh.q = *(const uint4*)base;
                wl.q = *(const uint4*)(base + 2048);
                a4 = __builtin_amdgcn_mfma_f32_16x16x32_f16(wh.b, bh.b, a4, 0, 0, 0);
                a4 = __builtin_amdgcn_mfma_f32_16x16x32_f16(wl.b, bh.b, a4, 0, 0, 0);
            }
            if (q == 0) {
                float4 o = make_float4(a4[0], a4[1], a4[2], a4[3]);
                if (wv == 0) {   // value stream gets bias
                    o.x += b4[0]; o.y += b4[1]; o.z += b4[2]; o.w += b4[3];
                }
                *(float4*)&OUTF[(wv * 16 + nn) * 4] = o;
            }
        }
        __syncthreads();

        // ---------------- per-point residual + reduction -------------------
        float contrib = 0.f;
        if (t < 16) {
            const int pp = t;
            const float* V   = &OUTF[(0  + pp) * 4];
            const float* DX  = &OUTF[(16 + pp) * 4];
            const float* DY  = &OUTF[(32 + pp) * 4];
            const float* LAP = &OUTF[(48 + pp) * 4];
            float r = V[0],  P = V[1],  u = V[2],  v = V[3];
            float rx = DX[0], Px = DX[1], ux = DX[2], vx = DX[3];
            float ry = DY[0], Py = DY[1], uy = DY[2], vy = DY[3];
            float rl = LAP[0], Pl = LAP[1], ul = LAP[2], vl = LAP[3];
            const float GI = 2.5f;  // 1/(gamma-1)

            float s = MUPART[pp] + MUPART[16 + pp] + MUPART[32 + pp]
                    + MUPART[48 + pp] + c2[0];
            float mu = 0.01f * s * s;

            float q2 = u * u + v * v;
            float E  = P * GI + 0.5f * r * q2;
            float Ex = Px * GI + 0.5f * rx * q2 + r * (u * ux + v * vx);
            float Ey = Py * GI + 0.5f * ry * q2 + r * (u * uy + v * vy);
            float EpP = E + P;

            float f1x = rx * u + r * ux;
            float f2x = rx * u * u + 2.f * r * u * ux + Px;
            float f3x = rx * u * v + r * ux * v + r * u * vx;
            float f4x = ux * EpP + u * (Ex + Px);

            float g1y = ry * v + r * vy;
            float g2y = ry * u * v + r * uy * v + r * u * vy;
            float g3y = ry * v * v + 2.f * r * v * vy + Py;
            float g4y = vy * EpP + v * (Ey + Py);

            float qx  = 2.f * (u * ux + v * vx);
            float qy  = 2.f * (u * uy + v * vy);
            float ql  = 2.f * (ux * ux + uy * uy + vx * vx + vy * vy)
                      + 2.f * (u * ul + v * vl);

            float U1s = rl;
            float U2s = rl * u + 2.f * (rx * ux + ry * uy) + r * ul;
            float U3s = rl * v + 2.f * (rx * vx + ry * vy) + r * vl;
            float U4s = Pl * GI
                      + 0.5f * (rl * q2 + 2.f * (rx * qx + ry * qy) + r * ql);

            float r1 = f1x + g1y - mu * U1s;
            float r2 = f2x + g2y - mu * U2s;
            float r3 = f3x + g3y - mu * U3s;
            float r4 = f4x + g4y - mu * U4s;

            contrib = (r1 * r1 + r2 * r2 + r3 * r3 + r4 * r4 + 0.1f * mu * mu)
                      * (1.0f / (float)NTRAIN);
        }
        if (t < 64) {
            contrib += __shfl_down(contrib, 32);
            contrib += __shfl_down(contrib, 16);
            contrib += __shfl_down(contrib, 8);
            contrib += __shfl_down(contrib, 4);
            contrib += __shfl_down(contrib, 2);
            contrib += __shfl_down(contrib, 1);
            if (t == 0) atomicAdd(out, contrib);
        }
    } else {
        // =================== BOUNDARY PATH (MFMA, 64 pts/block) ============
        unsigned short* ShU = (unsigned short*)SM;   // 64 x 136
        float* OUTB  = SM + 4352;   // 64 x 4
        float* BIASB = SM + 4608;   // 384 floats

        const int bb    = blockIdx.x - PHYS_BLOCKS;
        const int batch = bb >> 6;  // 0..3 (64 blocks each)
        const int lb    = bb & 63;
        const float* xs = (batch == 0) ? x_inlet
                        : (batch == 1) ? x_base
                        : (batch == 2) ? x_top : x_slip;
        const int base_pt = lb * 64;

        // ---- layer 0: 2 -> 128 (4 threads/pt, 32 units each) + biases ----
        {
            int p2 = t & 63, ug = t >> 6;
            float2 xy = *(const float2*)(xs + (base_pt + p2) * 2);
            float x = xy.x, y = xy.y;
            #pragma unroll
            for (int g = 0; g < 8; g++) {
                int u0 = ug * 32 + g * 4;
                F4 wa, wb, bbv;
                wa.v  = *(const float4*)(W0 + u0);
                wb.v  = *(const float4*)(W0 + 128 + u0);
                bbv.v = *(const float4*)(b0 + u0);
                float t0 = fast_tanh(x * wa.f[0] + y * wb.f[0] + bbv.f[0]);
                float t1 = fast_tanh(x * wa.f[1] + y * wb.f[1] + bbv.f[1]);
                float t2 = fast_tanh(x * wa.f[2] + y * wb.f[2] + bbv.f[2]);
                float t3 = fast_tanh(x * wa.f[3] + y * wb.f[3] + bbv.f[3]);
                uint2 d = make_uint2(pk2(t0, t1), pk2(t2, t3));
                *(uint2*)(ShU + p2 * 136 + u0) = d;
            }
            if (t < 128) {
                BIASB[t]       = b1[t];
                BIASB[128 + t] = b2[t];
                BIASB[256 + t] = b3[t];
            }
        }
        __syncthreads();

        // ---- hidden layers 1..3 via MFMA (W hi only, 4 point-tiles) ----
        #pragma unroll 1
        for (int l = 0; l < 3; l++) {
            const unsigned short* WpL = wsU + l * 32768;
            f32x4 acc[2][4];
            #pragma unroll
            for (int i = 0; i < 2; i++)
                #pragma unroll
                for (int n = 0; n < 4; n++) {
                    acc[i][n][0] = 0.f; acc[i][n][1] = 0.f;
                    acc[i][n][2] = 0.f; acc[i][n][3] = 0.f;
                }
            #pragma unroll
            for (int ks = 0; ks < 4; ks++) {
                FragU bh[4];
                #pragma unroll
                for (int n = 0; n < 4; n++)
                    bh[n].q = *(const uint4*)(ShU + (n * 16 + nn) * 136 + ks * 32 + q * 8);
                FragU wh[2];
                #pragma unroll
                for (int i = 0; i < 2; i++)
                    wh[i].q = *(const uint4*)(WpL + ((((2 * wv + i) * 4 + ks) * 64 + lane) << 3));
                #pragma unroll
                for (int i = 0; i < 2; i++)
                    #pragma unroll
                    for (int n = 0; n < 4; n++)
                        acc[i][n] = __builtin_amdgcn_mfma_f32_16x16x32_f16(
                            wh[i].b, bh[n].b, acc[i][n], 0, 0, 0);
            }
            __syncthreads();
            #pragma unroll
            for (int i = 0; i < 2; i++) {
                int ubase = (2 * wv + i) * 16 + q * 4;
                F4 bv; bv.v = *(const float4*)&BIASB[l * 128 + ubase];
                #pragma unroll
                for (int n = 0; n < 4; n++) {
                    float t0 = fast_tanh(acc[i][n][0] + bv.f[0]);
                    float t1 = fast_tanh(acc[i][n][1] + bv.f[1]);
                    float t2 = fast_tanh(acc[i][n][2] + bv.f[2]);
                    float t3 = fast_tanh(acc[i][n][3] + bv.f[3]);
                    uint2 d = make_uint2(pk2(t0, t1), pk2(t2, t3));
                    *(uint2*)(ShU + (n * 16 + nn) * 136 + ubase) = d;
                }
            }
            __syncthreads();
        }

        // ---- layer 4 via MFMA (padded W4, hi+lo), one point-tile/wave ----
        {
            const unsigned short* W4p = wsU + 102400;
            f32x4 a4 = {0.f, 0.f, 0.f, 0.f};
            #pragma unroll
            for (int ks = 0; ks < 4; ks++) {
                FragU bh, wh, wl;
                bh.q = *(const uint4*)(ShU + (wv * 16 + nn) * 136 + ks * 32 + q * 8);
                const unsigned short* base = W4p + ((ks * 64 + lane) << 3);
                wh.q = *(const uint4*)base;
                wl.q = *(const uint4*)(base + 2048);
                a4 = __builtin_amdgcn_mfma_f32_16x16x32_f16(wh.b, bh.b, a4, 0, 0, 0);
                a4 = __builtin_amdgcn_mfma_f32_16x16x32_f16(wl.b, bh.b, a4, 0, 0, 0);
            }
            if (q == 0) {
                float4 o = make_float4(a4[0] + b4[0], a4[1] + b4[1],
                                       a4[2] + b4[2], a4[3] + b4[3]);
                *(float4*)&OUTB[(wv * 16 + nn) * 4] = o;
            }
        }
        __syncthreads();

        float contrib = 0.f;
        if (t < 64) {
            float o0 = OUTB[t * 4 + 0], o1 = OUTB[t * 4 + 1];
            float o2 = OUTB[t * 4 + 2], o3 = OUTB[t * 4 + 3];
            float l;
            if (batch == 0) {
                float4 Ui = *(const float4*)(U_inlet + (base_pt + t) * 4);
                float d0 = o0 - Ui.x, d1 = o1 - Ui.y, d2 = o2 - Ui.z, d3 = o3 - Ui.w;
                l = d0 * d0 + d1 * d1 + d2 * d2 + d3 * d3;
            } else if (batch == 3) {
                const float sa = -0.17364817766693033f;  // sin(-pi/18)
                const float ca =  0.9848077530122080f;   // cos(-pi/18)
                float d = -o2 * sa + o3 * ca;
                l = d * d;
            } else {
                l = o3 * o3;
            }
            contrib = 10.0f * l * (1.0f / (float)NBDY);
        }
        if (t < 64) {
            contrib += __shfl_down(contrib, 32);
            contrib += __shfl_down(contrib, 16);
            contrib += __shfl_down(contrib, 8);
            contrib += __shfl_down(contrib, 4);
            contrib += __shfl_down(contrib, 2);
            contrib += __shfl_down(contrib, 1);
            if (t == 0) atomicAdd(out, contrib);
        }
    }
}

extern "C" void kernel_launch(void* const* d_in, const int* in_sizes, int n_in,
                              void* d_out, int out_size, void* d_ws, size_t ws_size,
                              hipStream_t stream) {
    const float* xt      = (const float*)d_in[0];
    const float* x_inlet = (const float*)d_in[1];
    const float* U_inlet = (const float*)d_in[2];
    const float* x_base  = (const float*)d_in[3];
    const float* x_top   = (const float*)d_in[4];
    const float* x_slip  = (const float*)d_in[5];
    const float* W0 = (const float*)d_in[6];
    const float* b0 = (const float*)d_in[7];
    const float* W1 = (const float*)d_in[8];
    const float* b1 = (const float*)d_in[9];
    const float* W2 = (const float*)d_in[10];
    const float* b2 = (const float*)d_in[11];
    const float* W3 = (const float*)d_in[12];
    const float* b3 = (const float*)d_in[13];
    const float* W4 = (const float*)d_in[14];
    const float* b4 = (const float*)d_in[15];
    const float* V0 = (const float*)d_in[16];
    const float* c0 = (const float*)d_in[17];
    const float* V1 = (const float*)d_in[18];
    const float* c1 = (const float*)d_in[19];
    const float* V2 = (const float*)d_in[20];
    const float* c2 = (const float*)d_in[21];
    float* out = (float*)d_out;
    unsigned short* wsU = (unsigned short*)d_ws;

    pack_w_kernel<<<26, 256, 0, stream>>>(W1, W2, W3, V1, W4, wsU, out);

    fused_kernel<<<PHYS_BLOCKS + BDY_BLOCKS, 256, 0, stream>>>(
        xt, x_inlet, U_inlet, x_base, x_top, x_slip,
        W0, b0, W1, b1, W2, b2, W3, b3, W4, b4,
        V0, c0, V1, c1, V2, c2, wsU, out);
}